// Round 9
// baseline (629.218 us; speedup 1.0000x reference)
//
#include <hip/hip_runtime.h>

// LocalAttention (Swin scrambled-window variant) — all four GEMMs on MFMA.
// Window map (verified pass R2/R3): n=b*1024+c*16+t ; c2=hi*32+lo ; p=r*8+s ;
// h=16t+8hi+r ; w=8lo+s ; mask index = n&1023.
// l2norm folds into k:  attn[i][j] = sum_c q[c][i] * (k[c][j]*0.125/(nq_c*nk_c)).
// Split-bf16 everywhere: x=hi+lo, D += Ah*Bh + Ah*Bl + Al*Bh (rel err ~2^-18).
//
// R11: pipelined front (P2 || DW ping-pong), (SHIFT,MASK,ROLL) template,
//      kk-addr XOR halving. 17 barriers.
// R12: back-end single-shot P6 + setprio:
//   - After P5 qT is DEAD -> vb FULL (16KB) into XT region; PT FULL (16KB)
//     into R2 (over dead K0/K1). P6 runs one 2-kk K-loop (acc in regs),
//     no i-half rebuilds, no divergent write guards. Barriers 17 -> 15.
//   - XTout -> R2 (YT, over dead PT); zero-span at smem[0,128) via magic
//     rows -128 (YTh) / -192 (YTl), key 0; projo back at smem+16384.
//   - T5: s_setprio(1) around each MFMA cluster (blocks at different
//     phases -> role diversity; m191 regime).
//   Arena: [0,16384) XTin->qT->vb->zero-span ; [16384,32768) bufA|bufB ->
//          K0|K1 -> PT -> XTout(YT) -> projo.

typedef __attribute__((ext_vector_type(8))) short bf8;
typedef __attribute__((ext_vector_type(4))) float f32x4;
#define MFMA(a, b, c) __builtin_amdgcn_mfma_f32_16x16x32_bf16(a, b, c, 0, 0, 0)

__device__ __forceinline__ int xkey(int p) { return ((p >> 3) ^ p) & 7; }
// bf16 64-wide regions: row p, col c (0..63) -> short index
__device__ __forceinline__ int xswz(int p, int c) { return p * 64 + (c ^ (xkey(p) << 3)); }
// bf16 32-wide regions (kT halves): row r, col c (0..31)
__device__ __forceinline__ int kswz(int r, int c) {
    return r * 32 + (c ^ ((((r >> 3) ^ (r >> 1)) & 3) << 3));
}
// scr fp32 (32 ch): stride 64, granule-4 XOR (uniform for P2 store + dw stencil)
__device__ __forceinline__ int sswz(int ch, int p) {
    return ch * 64 + (p ^ (((ch >> 1) & 7) << 2));
}
// projo fp32 (64 ch): stride 64, granule-8 XOR (uniform store, 2-way P8 read)
__device__ __forceinline__ int jswz(int ch, int p) {
    return ch * 64 + (p ^ (((ch >> 1) & 7) << 3));
}

// packed 2xf32 -> 2xbf16 (RNE). No builtin on gfx950 — inline asm (T12/m240).
__device__ __forceinline__ unsigned cvtpk(float a, float b) {
    unsigned r;
    asm("v_cvt_pk_bf16_f32 %0, %1, %2" : "=v"(r) : "v"(a), "v"(b));
    return r;
}

__device__ __forceinline__ void bsplit(float f, short& h, short& l) {
    unsigned u = __float_as_uint(f);
    unsigned hb = (u + 0x7FFFu + ((u >> 16) & 1u)) >> 16;
    float hf = __uint_as_float(hb << 16);
    float r = f - hf;
    unsigned u2 = __float_as_uint(r);
    unsigned lb = (u2 + 0x7FFFu + ((u2 >> 16) & 1u)) >> 16;
    h = (short)hb; l = (short)lb;
}
// a in low half, b in high half. hi = RNE-bf16(x); lo = RNE-bf16(x - hi).
__device__ __forceinline__ void bsplit2(float a, float b, unsigned& hw, unsigned& lw) {
    hw = cvtpk(a, b);
    float ra = a - __uint_as_float(hw << 16);
    float rb = b - __uint_as_float(hw & 0xFFFF0000u);
    lw = cvtpk(ra, rb);
}

// ---- qkv 1x1 weight fragments: [kk(2)][tt(12)][lane(64)][j(8)]  B[n=oc][k=ic] ----
__global__ void k_fq(const float* __restrict__ wq, short* __restrict__ oh, short* __restrict__ ol) {
    int bx = blockIdx.x;                 // kk*12 + tt
    int kk = bx / 12, tt = bx % 12;
    int tid = threadIdx.x;               // 512
    int lane = tid >> 3, j = tid & 7;
    int oc = tt * 16 + (lane & 15);
    int ic = kk * 32 + ((lane >> 4) << 3) + j;
    short h, l; bsplit(wq[oc * 64 + ic], h, l);
    oh[bx * 512 + tid] = h; ol[bx * 512 + tid] = l;
}
// ---- proj 3x3 weight fragments: [tap(9)][kk(2)][tt(4)][lane(64)][j(8)] ----
__global__ void k_fp(const float* __restrict__ wp, short* __restrict__ oh, short* __restrict__ ol) {
    int bx = blockIdx.x;                 // tap*8 + kk*4 + tt
    int tap = bx >> 3, kk = (bx >> 2) & 1, tt = bx & 3;
    int tid = threadIdx.x;
    int lane = tid >> 3, j = tid & 7;
    int oc = tt * 16 + (lane & 15);
    int ic = kk * 32 + ((lane >> 4) << 3) + j;
    short h, l; bsplit(wp[(oc * 64 + ic) * 9 + tap], h, l);
    oh[bx * 512 + tid] = h; ol[bx * 512 + tid] = l;
}

// dw3x3 for ONE channel (local ch 0..31 in scr), one output row, zero pad.
__device__ __forceinline__ void dw_one(const float* scr, const float* wd,
                                       int ch, int row, float o[8]) {
    float w9[9];
    #pragma unroll
    for (int tp = 0; tp < 9; ++tp) w9[tp] = wd[tp];
    float e[3][10];
    #pragma unroll
    for (int k3 = 0; k3 < 3; ++k3) {
        int rr = row - 1 + k3;
        e[k3][0] = 0.f; e[k3][9] = 0.f;
        if ((unsigned)rr < 8u) {
            float4 a = *(const float4*)&scr[sswz(ch, rr * 8)];
            float4 b = *(const float4*)&scr[sswz(ch, rr * 8 + 4)];
            e[k3][1] = a.x; e[k3][2] = a.y; e[k3][3] = a.z; e[k3][4] = a.w;
            e[k3][5] = b.x; e[k3][6] = b.y; e[k3][7] = b.z; e[k3][8] = b.w;
        } else {
            #pragma unroll
            for (int q2 = 1; q2 < 9; ++q2) e[k3][q2] = 0.f;
        }
    }
    #pragma unroll
    for (int s = 0; s < 8; ++s) {
        float a = 0.f;
        #pragma unroll
        for (int k3 = 0; k3 < 3; ++k3)
            #pragma unroll
            for (int dx = 0; dx < 3; ++dx)
                a = fmaf(w9[k3 * 3 + dx], e[k3][s + dx], a);
        o[s] = a;
    }
}

__device__ __forceinline__ float norm8(const float d[8]) {
    float ss = 0.f;
    #pragma unroll
    for (int s = 0; s < 8; ++s) ss = fmaf(d[s], d[s], ss);
    ss += __shfl_xor(ss, 1); ss += __shfl_xor(ss, 2); ss += __shfl_xor(ss, 4);
    return fmaxf(sqrtf(ss), 1e-12f);
}

// P2 chunk: 64px x 32oc x 64ic MFMA 1x1, XTin -> scr.
// chunk selects oc-16-tile pair: 0,1=q ; 2,3=k ; 4,5=v (tt = chunk*2+nh).
__device__ __forceinline__ void p2_chunk32(const short* XTh, const short* XTl,
                                           const short* bqh, const short* bql,
                                           float* scr, int chunk,
                                           int mh, int nh, int col, int quad, int qo8, int lane)
{
    f32x4 acc[2];
    #pragma unroll
    for (int mt = 0; mt < 2; ++mt) acc[mt] = (f32x4){0.f, 0.f, 0.f, 0.f};
    int ad0[2];
    #pragma unroll
    for (int mt = 0; mt < 2; ++mt) {
        int row = (mh * 2 + mt) * 16 + col;
        ad0[mt] = row * 64 + (qo8 ^ (xkey(row) << 3));
    }
    __builtin_amdgcn_s_setprio(1);
    #pragma unroll
    for (int kk = 0; kk < 2; ++kk) {
        bf8 Ah[2], Al[2];
        #pragma unroll
        for (int mt = 0; mt < 2; ++mt) {
            int ad = ad0[mt] ^ (kk << 5);
            Ah[mt] = *(const bf8*)&XTh[ad];
            Al[mt] = *(const bf8*)&XTl[ad];
        }
        int tt = chunk * 2 + nh;
        bf8 Bh = *(const bf8*)&bqh[((kk * 12 + tt) * 64 + lane) * 8];
        bf8 Bl = *(const bf8*)&bql[((kk * 12 + tt) * 64 + lane) * 8];
        #pragma unroll
        for (int mt = 0; mt < 2; ++mt) {
            acc[mt] = MFMA(Ah[mt], Bh, acc[mt]);
            acc[mt] = MFMA(Ah[mt], Bl, acc[mt]);
            acc[mt] = MFMA(Al[mt], Bh, acc[mt]);
        }
    }
    __builtin_amdgcn_s_setprio(0);
    #pragma unroll
    for (int mt = 0; mt < 2; ++mt) {
        int ocl = nh * 16 + col;
        int p0 = (mh * 2 + mt) * 16 + quad * 4;
        *(f32x4*)&scr[sswz(ocl, p0)] = acc[mt];
    }
}

template<int SHIFT, int MASK, int ROLL>
__global__ __launch_bounds__(256, 4)
void k_fused(const float* __restrict__ in,
             const short* __restrict__ bqh, const short* __restrict__ bql,
             const float* __restrict__ wdw,
             const short* __restrict__ bph, const short* __restrict__ bpl,
             float* __restrict__ out)
{
    __shared__ __align__(16) char smem[32768];
    short* XTh = (short*)smem;                 // [0,16384): XTin -> qT -> vb
    short* XTl = (short*)(smem + 8192);
    float* bufA = (float*)(smem + 16384);      // front scr ping (8KB)
    float* bufB = (float*)(smem + 24576);      // front scr pong (8KB)
    short* K0h = (short*)(smem + 16384);       // kT c<32 hi (4KB)
    short* K0l = (short*)(smem + 20480);       // kT c<32 lo (4KB)
    short* K1h = (short*)(smem + 24576);       // kT c>=32 hi (4KB)
    short* K1l = (short*)(smem + 28672);       // kT c>=32 lo (4KB)
    short* vbh = (short*)smem;                 // P6: vb FULL (over dead qT)
    short* vbl = (short*)(smem + 8192);
    short* PTh = (short*)(smem + 16384);       // P6: PT FULL (over dead K0/K1)
    short* PTl = (short*)(smem + 24576);
    short* YTh = (short*)(smem + 16384);       // XTout (over dead PT)
    short* YTl = (short*)(smem + 24576);
    float* projo = (float*)(smem + 16384);     // after P7 (over dead YT)

    const int tid = threadIdx.x, lane = tid & 63, wv = tid >> 6;
    const int col = lane & 15, quad = lane >> 4, qo8 = quad * 8;
    const int mh = wv & 1, nh = wv >> 1;
    const int ch = tid >> 3, rrow = tid & 7;   // DW map: 1 channel/thread
    const int n = blockIdx.x;
    const int b = n >> 10, c = (n >> 4) & 63, t = n & 15;
    const size_t base = ((size_t)(b * 64 + c)) << 16;

    // ---- P1: load window, split via cvt_pk pairs, XTin[p][c2] ----
    #pragma unroll
    for (int k = 0; k < 16; k += 2) {
        int o0 = tid + k * 256, o1 = o0 + 256;
        float v0, v1;
        if (SHIFT == 0) {
            const float* src = in + base + (size_t)t * 4096;
            v0 = src[o0]; v1 = src[o1];
        } else {
            int hi0 = o0 >> 11, r0 = (o0 >> 8) & 7, lo0 = (o0 >> 3) & 31, s0 = o0 & 7;
            int hi1 = o1 >> 11, r1 = (o1 >> 8) & 7, lo1 = (o1 >> 3) & 31, s1 = o1 & 7;
            v0 = in[base + (size_t)(((t * 16 + hi0 * 8 + r0) + SHIFT) & 255) * 256
                         + (((lo0 * 8 + s0) + SHIFT) & 255)];
            v1 = in[base + (size_t)(((t * 16 + hi1 * 8 + r1) + SHIFT) & 255) * 256
                         + (((lo1 * 8 + s1) + SHIFT) & 255)];
        }
        unsigned hw, lw; bsplit2(v0, v1, hw, lw);
        int hi0 = o0 >> 11, r0 = (o0 >> 8) & 7, lo0 = (o0 >> 3) & 31, s0 = o0 & 7;
        int hi1 = o1 >> 11, r1 = (o1 >> 8) & 7, lo1 = (o1 >> 3) & 31, s1 = o1 & 7;
        int ad0 = xswz(r0 * 8 + s0, hi0 * 32 + lo0);
        int ad1 = xswz(r1 * 8 + s1, hi1 * 32 + lo1);
        XTh[ad0] = (short)hw; XTh[ad1] = (short)(hw >> 16);
        XTl[ad0] = (short)lw; XTl[ad1] = (short)(lw >> 16);
    }
    __syncthreads();   // (1)

    // preconverted packed bf16 words (straight-line SROA-safe; rule #20)
    unsigned qAh[4], qAl[4], qBh[4], qBl[4];
    unsigned vAh[4], vAl[4], vBh[4], vBl[4];
    unsigned k0h[4], k0l[4], k1h[4], k1l[4];
    float nqA, nqB;

    // ---- front pipeline: P2(next) || DW(prev), A/B ping-pong, 1 barrier/phase ----
    p2_chunk32(XTh, XTl, bqh, bql, bufA, 0, mh, nh, col, quad, qo8, lane);
    __syncthreads();   // (2)
    p2_chunk32(XTh, XTl, bqh, bql, bufB, 1, mh, nh, col, quad, qo8, lane);
    {
        float d[8];
        dw_one(bufA, wdw + ch * 9, ch, rrow, d);
        nqA = norm8(d);
        #pragma unroll
        for (int q2 = 0; q2 < 4; ++q2) bsplit2(d[2 * q2], d[2 * q2 + 1], qAh[q2], qAl[q2]);
    }
    __syncthreads();   // (3)
    p2_chunk32(XTh, XTl, bqh, bql, bufA, 4, mh, nh, col, quad, qo8, lane);
    {
        float d[8];
        dw_one(bufB, wdw + (32 + ch) * 9, ch, rrow, d);
        nqB = norm8(d);
        #pragma unroll
        for (int q2 = 0; q2 < 4; ++q2) bsplit2(d[2 * q2], d[2 * q2 + 1], qBh[q2], qBl[q2]);
    }
    __syncthreads();   // (4)
    p2_chunk32(XTh, XTl, bqh, bql, bufB, 5, mh, nh, col, quad, qo8, lane);
    {
        float d[8];
        dw_one(bufA, wdw + (128 + ch) * 9, ch, rrow, d);
        #pragma unroll
        for (int q2 = 0; q2 < 4; ++q2) bsplit2(d[2 * q2], d[2 * q2 + 1], vAh[q2], vAl[q2]);
    }
    __syncthreads();   // (5)
    p2_chunk32(XTh, XTl, bqh, bql, bufA, 2, mh, nh, col, quad, qo8, lane);
    {
        float d[8];
        dw_one(bufB, wdw + (160 + ch) * 9, ch, rrow, d);
        #pragma unroll
        for (int q2 = 0; q2 < 4; ++q2) bsplit2(d[2 * q2], d[2 * q2 + 1], vBh[q2], vBl[q2]);
    }
    __syncthreads();   // (6)
    p2_chunk32(XTh, XTl, bqh, bql, bufB, 3, mh, nh, col, quad, qo8, lane);
    {
        float d[8];
        dw_one(bufA, wdw + (64 + ch) * 9, ch, rrow, d);
        float sc = 0.125f / (nqA * norm8(d));
        #pragma unroll
        for (int s = 0; s < 8; ++s) d[s] *= sc;
        #pragma unroll
        for (int q2 = 0; q2 < 4; ++q2) bsplit2(d[2 * q2], d[2 * q2 + 1], k0h[q2], k0l[q2]);
    }
    __syncthreads();   // (7)
    // ph7: DWk1(B) + scale || scatter dk0 -> K0 (=A bytes) || scatter dq -> qT (XT)
    {
        float d[8];
        dw_one(bufB, wdw + (96 + ch) * 9, ch, rrow, d);
        float sc = 0.125f / (nqB * norm8(d));
        #pragma unroll
        for (int s = 0; s < 8; ++s) d[s] *= sc;
        #pragma unroll
        for (int q2 = 0; q2 < 4; ++q2) bsplit2(d[2 * q2], d[2 * q2 + 1], k1h[q2], k1l[q2]);
    }
    #pragma unroll
    for (int q2 = 0; q2 < 4; ++q2) {
        int p0 = rrow * 8 + 2 * q2;
        int a0 = kswz(p0, ch), a1 = kswz(p0 + 1, ch);
        K0h[a0] = (short)k0h[q2]; K0h[a1] = (short)(k0h[q2] >> 16);
        K0l[a0] = (short)k0l[q2]; K0l[a1] = (short)(k0l[q2] >> 16);
        int x0 = xswz(p0, ch), x1 = xswz(p0 + 1, ch);
        XTh[x0] = (short)qAh[q2]; XTh[x1] = (short)(qAh[q2] >> 16);
        XTl[x0] = (short)qAl[q2]; XTl[x1] = (short)(qAl[q2] >> 16);
        int cg = 32 + ch;
        int y0 = xswz(p0, cg), y1 = xswz(p0 + 1, cg);
        XTh[y0] = (short)qBh[q2]; XTh[y1] = (short)(qBh[q2] >> 16);
        XTl[y0] = (short)qBl[q2]; XTl[y1] = (short)(qBl[q2] >> 16);
    }
    __syncthreads();   // (8)
    // ph8: scatter dk1 -> K1 (=B bytes)
    #pragma unroll
    for (int q2 = 0; q2 < 4; ++q2) {
        int p0 = rrow * 8 + 2 * q2;
        int a0 = kswz(p0, ch), a1 = kswz(p0 + 1, ch);
        K1h[a0] = (short)k1h[q2]; K1h[a1] = (short)(k1h[q2] >> 16);
        K1l[a0] = (short)k1l[q2]; K1l[a1] = (short)(k1l[q2] >> 16);
    }
    __syncthreads();   // (9) qT/kT ready

    // ---- P5: MFMA QK^T (M=i rows wv*16.., N=j all 64, K=c) + mask + softmax ----
    f32x4 at[4];
    #pragma unroll
    for (int nt = 0; nt < 4; ++nt) at[nt] = (f32x4){0.f, 0.f, 0.f, 0.f};
    {
        bf8 Ah[2], Al[2];
        int rowA = wv * 16 + col;
        int adA0 = rowA * 64 + (qo8 ^ (xkey(rowA) << 3));
        #pragma unroll
        for (int kk = 0; kk < 2; ++kk) {
            int ad = adA0 ^ (kk << 5);
            Ah[kk] = *(const bf8*)&XTh[ad];   // qT
            Al[kk] = *(const bf8*)&XTl[ad];
        }
        __builtin_amdgcn_s_setprio(1);
        #pragma unroll
        for (int kk = 0; kk < 2; ++kk) {
            const short* Bph = kk ? K1h : K0h;
            const short* Bpl = kk ? K1l : K0l;
            #pragma unroll
            for (int nt = 0; nt < 4; ++nt) {
                int rowB = nt * 16 + col;
                int ad = kswz(rowB, qo8);
                bf8 Bh = *(const bf8*)&Bph[ad];
                bf8 Bl = *(const bf8*)&Bpl[ad];
                at[nt] = MFMA(Ah[kk], Bh, at[nt]);
                at[nt] = MFMA(Ah[kk], Bl, at[nt]);
                at[nt] = MFMA(Al[kk], Bh, at[nt]);
            }
        }
        __builtin_amdgcn_s_setprio(0);
    }
    if (MASK) {
        const int widx = n & 1023;
        const int hn_m = widx >> 5, wn_m = widx & 31;
        #pragma unroll
        for (int nt = 0; nt < 4; ++nt) {
            int j = nt * 16 + col;
            int rj = ((hn_m == 31) ? (((j >> 3) < 4) ? 1 : 2) : 0) * 3
                   + ((wn_m == 31) ? (((j & 7) < 4) ? 1 : 2) : 0);
            #pragma unroll
            for (int rg = 0; rg < 4; ++rg) {
                int i = wv * 16 + quad * 4 + rg;
                int ri = ((hn_m == 31) ? (((i >> 3) < 4) ? 1 : 2) : 0) * 3
                       + ((wn_m == 31) ? (((i & 7) < 4) ? 1 : 2) : 0);
                if (ri != rj) at[nt][rg] = at[nt][rg] - 100.f;
            }
        }
    }
    unsigned Ph[4][2], Pl[4][2];
    {
        float Pv[4][4];
        #pragma unroll
        for (int rg = 0; rg < 4; ++rg) {
            float m = fmaxf(fmaxf(at[0][rg], at[1][rg]), fmaxf(at[2][rg], at[3][rg]));
            m = fmaxf(m, __shfl_xor(m, 1)); m = fmaxf(m, __shfl_xor(m, 2));
            m = fmaxf(m, __shfl_xor(m, 4)); m = fmaxf(m, __shfl_xor(m, 8));
            float e0 = __expf(at[0][rg] - m), e1 = __expf(at[1][rg] - m);
            float e2 = __expf(at[2][rg] - m), e3 = __expf(at[3][rg] - m);
            float s = e0 + e1 + e2 + e3;
            s += __shfl_xor(s, 1); s += __shfl_xor(s, 2);
            s += __shfl_xor(s, 4); s += __shfl_xor(s, 8);
            float is = 1.0f / s;
            Pv[0][rg] = e0 * is; Pv[1][rg] = e1 * is; Pv[2][rg] = e2 * is; Pv[3][rg] = e3 * is;
        }
        #pragma unroll
        for (int nt = 0; nt < 4; ++nt)
            #pragma unroll
            for (int rp = 0; rp < 2; ++rp)
                bsplit2(Pv[nt][2 * rp], Pv[nt][2 * rp + 1], Ph[nt][rp], Pl[nt][rp]);
    }
    __syncthreads();   // (10) all qT/kT reads done; XT and R2 reusable

    // ---- vb FULL (over dead qT) + PT FULL (over dead K0/K1), uniform writes ----
    {
        int adA = ch * 64 + ((rrow * 8) ^ (xkey(ch) << 3));
        *(uint4*)&vbh[adA] = (uint4){vAh[0], vAh[1], vAh[2], vAh[3]};
        *(uint4*)&vbl[adA] = (uint4){vAl[0], vAl[1], vAl[2], vAl[3]};
        int cg = 32 + ch;
        int adB = cg * 64 + ((rrow * 8) ^ (xkey(cg) << 3));
        *(uint4*)&vbh[adB] = (uint4){vBh[0], vBh[1], vBh[2], vBh[3]};
        *(uint4*)&vbl[adB] = (uint4){vBl[0], vBl[1], vBl[2], vBl[3]};
    }
    #pragma unroll
    for (int nt = 0; nt < 4; ++nt) {
        int j = nt * 16 + col;
        #pragma unroll
        for (int rp = 0; rp < 2; ++rp) {
            int i0 = wv * 16 + quad * 4 + 2 * rp;
            int ad = j * 64 + (i0 ^ (xkey(j) << 3));
            *(unsigned*)&PTh[ad] = Ph[nt][rp];
            *(unsigned*)&PTl[ad] = Pl[nt][rp];
        }
    }
    __syncthreads();   // (11)

    // ---- P6 single-shot: M=c, N=j, K=i (2 kk-halves), acc in regs ----
    f32x4 av[2][2];
    #pragma unroll
    for (int mt = 0; mt < 2; ++mt)
        #pragma unroll
        for (int nt = 0; nt < 2; ++nt) av[mt][nt] = (f32x4){0.f, 0.f, 0.f, 0.f};
    {
        int adA0[2], adB0[2];
        #pragma unroll
        for (int mt = 0; mt < 2; ++mt) {
            int row = (mh * 2 + mt) * 16 + col;
            adA0[mt] = row * 64 + (qo8 ^ (xkey(row) << 3));
        }
        #pragma unroll
        for (int nt = 0; nt < 2; ++nt) {
            int rowB = (nh * 2 + nt) * 16 + col;
            adB0[nt] = rowB * 64 + (qo8 ^ (xkey(rowB) << 3));
        }
        __builtin_amdgcn_s_setprio(1);
        #pragma unroll
        for (int kk = 0; kk < 2; ++kk) {
            bf8 Ah[2], Al[2], Bh[2], Bl[2];
            #pragma unroll
            for (int mt = 0; mt < 2; ++mt) {
                Ah[mt] = *(const bf8*)&vbh[adA0[mt] ^ (kk << 5)];
                Al[mt] = *(const bf8*)&vbl[adA0[mt] ^ (kk << 5)];
            }
            #pragma unroll
            for (int nt = 0; nt < 2; ++nt) {
                Bh[nt] = *(const bf8*)&PTh[adB0[nt] ^ (kk << 5)];
                Bl[nt] = *(const bf8*)&PTl[adB0[nt] ^ (kk << 5)];
            }
            #pragma unroll
            for (int mt = 0; mt < 2; ++mt)
                #pragma unroll
                for (int nt = 0; nt < 2; ++nt) {
                    av[mt][nt] = MFMA(Ah[mt], Bh[nt], av[mt][nt]);
                    av[mt][nt] = MFMA(Ah[mt], Bl[nt], av[mt][nt]);
                    av[mt][nt] = MFMA(Al[mt], Bh[nt], av[mt][nt]);
                }
        }
        __builtin_amdgcn_s_setprio(0);
    }
    __syncthreads();   // (12) vb/PT reads done; R2 reusable

    // ---- XTout -> YT (over dead PT) ; zero span at smem[0,128) (over dead vb) ----
    #pragma unroll
    for (int nt = 0; nt < 2; ++nt) {
        int j = (nh * 2 + nt) * 16 + col;
        #pragma unroll
        for (int mt = 0; mt < 2; ++mt) {
            int c0 = (mh * 2 + mt) * 16 + quad * 4;
            #pragma unroll
            for (int rp = 0; rp < 2; ++rp) {
                unsigned hw, lw; bsplit2(av[mt][nt][2 * rp], av[mt][nt][2 * rp + 1], hw, lw);
                int ad = j * 64 + ((c0 + 2 * rp) ^ (xkey(j) << 3));
                *(unsigned*)&YTh[ad] = hw;
                *(unsigned*)&YTl[ad] = lw;
            }
        }
    }
    if (tid < 32) ((unsigned*)smem)[tid] = 0u;
    __syncthreads();   // (13)

    // ---- P7: MFMA proj conv = 9 shifted GEMMs. M=p, N=oc, K=ic.
    //      OOB -> zero span smem[0,128): magic offsets qo8-8192 (YTh base) /
    //      qo8-12288 (YTl base); key 0; bit5 of offset clear so ^(kk<<5) valid. ----
    {
        f32x4 ap[2][2];
        #pragma unroll
        for (int mt = 0; mt < 2; ++mt)
            #pragma unroll
            for (int nt = 0; nt < 2; ++nt) ap[mt][nt] = (f32x4){0.f, 0.f, 0.f, 0.f};
        const int smc = col & 7;
        #pragma unroll 1
        for (int tap = 0; tap < 9; ++tap) {
            int dy = (tap >= 6) ? 1 : ((tap >= 3) ? 0 : -1);
            int dx = tap - (dy + 1) * 3 - 1;
            int bh0[2], bl0[2];
            #pragma unroll
            for (int mt = 0; mt < 2; ++mt) {
                int rr = (mh * 2 + mt) * 2 + (col >> 3) + dy;
                int ss = smc + dx;
                bool ok = ((unsigned)rr < 8u) && ((unsigned)ss < 8u);
                int row = rr * 8 + ss;
                int good = row * 64 + (qo8 ^ (xkey(row) << 3));
                bh0[mt] = ok ? good : (qo8 - 8192);
                bl0[mt] = ok ? good : (qo8 - 12288);
            }
            #pragma unroll
            for (int kk = 0; kk < 2; ++kk) {
                bf8 Bh[2], Bl[2], Ah[2], Al[2];
                #pragma unroll
                for (int nt = 0; nt < 2; ++nt) {
                    int bi = (((tap * 2 + kk) * 4 + (nh * 2 + nt)) * 64 + lane) * 8;
                    Bh[nt] = *(const bf8*)&bph[bi];
                    Bl[nt] = *(const bf8*)&bpl[bi];
                }
                #pragma unroll
                for (int mt = 0; mt < 2; ++mt) {
                    Ah[mt] = *(const bf8*)&YTh[bh0[mt] ^ (kk << 5)];
                    Al[mt] = *(const bf8*)&YTl[bl0[mt] ^ (kk << 5)];
                }
                __builtin_amdgcn_s_setprio(1);
                #pragma unroll
                for (int mt = 0; mt < 2; ++mt)
                    #pragma unroll
                    for (int nt = 0; nt < 2; ++nt) {
                        ap[mt][nt] = MFMA(Ah[mt], Bh[nt], ap[mt][nt]);
                        ap[mt][nt] = MFMA(Ah[mt], Bl[nt], ap[mt][nt]);
                        ap[mt][nt] = MFMA(Al[mt], Bh[nt], ap[mt][nt]);
                    }
                __builtin_amdgcn_s_setprio(0);
            }
        }
        __syncthreads();   // (14) all tap reads (incl. zero span) done
        #pragma unroll
        for (int nt = 0; nt < 2; ++nt) {
            int oc = (nh * 2 + nt) * 16 + col;
            #pragma unroll
            for (int mt = 0; mt < 2; ++mt) {
                int p0 = (mh * 2 + mt) * 16 + quad * 4;
                *(f32x4*)&projo[jswz(oc, p0)] = ap[mt][nt];
            }
        }
    }
    __syncthreads();   // (15)

    // ---- P8: window reverse + roll, coalesced image-order stores ----
    #pragma unroll
    for (int k = 0; k < 16; ++k) {
        int o = tid + k * 256;
        int hi = o >> 11, r = (o >> 8) & 7, lo = (o >> 3) & 31, s = o & 7;
        int c2 = hi * 32 + lo;
        float v = projo[jswz(c2, r * 8 + s)];
        if (ROLL == 0) {
            float* dst = out + base + (size_t)t * 4096;
            dst[o] = v;
        } else {
            int h2 = t * 16 + hi * 8 + r, w2 = lo * 8 + s;
            out[base + (size_t)((h2 + ROLL) & 255) * 256 + ((w2 + ROLL) & 255)] = v;
        }
    }
}

extern "C" void kernel_launch(void* const* d_in, const int* in_sizes, int n_in,
                              void* d_out, int out_size, void* d_ws, size_t ws_size,
                              hipStream_t stream)
{
    const float* x      = (const float*)d_in[0];
    const float* wqkv0  = (const float*)d_in[1];
    const float* wdw0   = (const float*)d_in[2];
    const float* wproj0 = (const float*)d_in[3];
    const float* wqkv1  = (const float*)d_in[4];
    const float* wdw1   = (const float*)d_in[5];
    const float* wproj1 = (const float*)d_in[6];
    float* out = (float*)d_out;

    float* tmp = (float*)d_ws;                       // 33,554,432 floats (134 MB)
    short* fb  = (short*)(tmp + 33554432);
    short* bq0h = fb;                                // 12288 each
    short* bq0l = fb + 12288;
    short* bq1h = fb + 24576;
    short* bq1l = fb + 36864;
    short* bp0h = fb + 49152;                        // 36864 each
    short* bp0l = fb + 86016;
    short* bp1h = fb + 122880;
    short* bp1l = fb + 159744;

    hipLaunchKernelGGL(k_fq, dim3(24), dim3(512), 0, stream, wqkv0, bq0h, bq0l);
    hipLaunchKernelGGL(k_fq, dim3(24), dim3(512), 0, stream, wqkv1, bq1h, bq1l);
    hipLaunchKernelGGL(k_fp, dim3(72), dim3(512), 0, stream, wproj0, bp0h, bp0l);
    hipLaunchKernelGGL(k_fp, dim3(72), dim3(512), 0, stream, wproj1, bp1h, bp1l);

    // pass 1: x -> tmp (no shift/mask/roll; specialized instantiation)
    hipLaunchKernelGGL(HIP_KERNEL_NAME(k_fused<0, 0, 0>), dim3(8192), dim3(256), 0, stream,
                       x, bq0h, bq0l, wdw0, bp0h, bp0l, tmp);
    // pass 2: tmp -> out (shift +4 read, Swin mask, roll +4 write)
    hipLaunchKernelGGL(HIP_KERNEL_NAME(k_fused<4, 1, 4>), dim3(8192), dim3(256), 0, stream,
                       tmp, bq1h, bq1l, wdw1, bp1h, bp1l, out);
}